// Round 11
// baseline (109.218 us; speedup 1.0000x reference)
//
#include <hip/hip_runtime.h>
#include <hip/hip_fp16.h>

#define NN 50000      // nodes
#define FF 128        // features
#define NE 800000     // edges
#define NT 5000       // train ids
#define NF (NN * FF)  // 6,400,000
#define NBKT 196      // coarse buckets: row>>8 in [0,196)
#define BCAP 8192     // bucket capacity (avg 4082)
#define PADCOL 50000u // zero Q row
#define P1BLK 98      // edge-scatter blocks in fused kernel
#define PACKN (NF / 4 + FF / 4)          // pack work items (u32x4 each)
#define PACKB ((PACKN + 1023) / 1024)    // 1563
#define TRNN (NT * 32)                   // train overwrite items
#define TRNB ((TRNN + 1023) / 1024)      // 157

typedef __attribute__((ext_vector_type(8))) short bf16x8;
typedef __attribute__((ext_vector_type(4))) float f32x4;
typedef __attribute__((ext_vector_type(4))) unsigned u32x4;
typedef __attribute__((ext_vector_type(2))) unsigned u32x2;
typedef __attribute__((ext_vector_type(4))) int i32x4;

__device__ __forceinline__ unsigned bf16_rne(float f) {
    unsigned u = __float_as_uint(f);
    return (u + 0x7FFFu + ((u >> 16) & 1u)) >> 16;
}

// ---------- tiny init: zero bucket cursors ----------
__global__ void k_init(int* __restrict__ gcur) {
    if (threadIdx.x < 256) gcur[threadIdx.x] = 0;
}

// ---------- fused: blocks 0..P1BLK-1 edge-scatter; rest pack Q ----------
__global__ __launch_bounds__(1024)
void k_sp(const int* __restrict__ rows, const int* __restrict__ cols,
          const float* __restrict__ adj, const float* __restrict__ M,
          const float* __restrict__ x, unsigned* __restrict__ Q,
          int* __restrict__ gcur, unsigned long long* __restrict__ ebuf) {
    int t = threadIdx.x;
    if (blockIdx.x >= P1BLK) {
        // ---- pack part: Q[n][f] = (bf16(sigmoid) | bf16(sig*x)<<16) ----
        int i4 = (blockIdx.x - P1BLK) * 1024 + t;
        if (i4 >= PACKN) return;
        u32x4* Q4 = reinterpret_cast<u32x4*>(Q);
        if (i4 >= NF / 4) {  // zero pad row (node NN)
            u32x4 z = {0, 0, 0, 0};
            Q4[i4] = z;
            return;
        }
        f32x4 m = __builtin_nontemporal_load(reinterpret_cast<const f32x4*>(M) + i4);
        f32x4 xv = __builtin_nontemporal_load(reinterpret_cast<const f32x4*>(x) + i4);
        float me0 = 1.0f / (1.0f + __expf(-m.x));
        float me1 = 1.0f / (1.0f + __expf(-m.y));
        float me2 = 1.0f / (1.0f + __expf(-m.z));
        float me3 = 1.0f / (1.0f + __expf(-m.w));
        u32x4 q;
        q.x = bf16_rne(me0) | (bf16_rne(me0 * xv.x) << 16);
        q.y = bf16_rne(me1) | (bf16_rne(me1 * xv.y) << 16);
        q.z = bf16_rne(me2) | (bf16_rne(me2 * xv.z) << 16);
        q.w = bf16_rne(me3) | (bf16_rne(me3 * xv.w) << 16);
        Q4[i4] = q;
        return;
    }
    // ---- edge-scatter part ----
    __shared__ int hist[256];
    __shared__ int cur[256];
    if (t < 256) hist[t] = 0;
    __syncthreads();
    int base = blockIdx.x * 8192;
    int r[8], c[8], bkt[8];
    float a[8];
#pragma unroll
    for (int k = 0; k < 8; ++k) {
        int idx = base + k * 1024 + t;
        bool v = idx < NE;
        r[k] = v ? rows[idx] : 0;
        c[k] = v ? cols[idx] : 0;
        a[k] = v ? adj[idx] : 0.f;
        bkt[k] = v ? (r[k] >> 8) : -1;
        if (v) atomicAdd(&hist[bkt[k]], 1);
    }
    __syncthreads();
    if (t < 256) {
        int cnt = hist[t];
        int b = 0;
        if (cnt > 0) b = atomicAdd(&gcur[t], cnt);
        cur[t] = b;
    }
    __syncthreads();
#pragma unroll
    for (int k = 0; k < 8; ++k) {
        if (bkt[k] >= 0) {
            int p = atomicAdd(&cur[bkt[k]], 1);
            if (p < BCAP) {
                unsigned h = (unsigned)__half_as_ushort(__float2half_rn(a[k]));
                unsigned pk = (unsigned)c[k] | (h << 16);
                ebuf[(size_t)bkt[k] * BCAP + p] =
                    ((unsigned long long)(r[k] & 255) << 32) | pk;
            }
        }
    }
}

// ---------- pass2 (+train overwrite blocks) ----------
__global__ __launch_bounds__(1024)
void k_pass2(const int* __restrict__ gcur,
             const unsigned long long* __restrict__ ebuf,
             unsigned* __restrict__ gedges, int* __restrict__ offsets,
             const int* __restrict__ train, const float* __restrict__ x,
             unsigned* __restrict__ Q) {
    int t = threadIdx.x;
    if (blockIdx.x >= NBKT) {
        // ---- train-row overwrite: me=1, g=bf16(x) (after pack) ----
        int g = (blockIdx.x - NBKT) * 1024 + t;
        if (g < TRNN) {
            int ti = g >> 5;
            int f4 = g & 31;
            int id = train[ti];
            f32x4 xv = reinterpret_cast<const f32x4*>(x)[id * 32 + f4];
            u32x4 q;
            q.x = 0x3F80u | (bf16_rne(xv.x) << 16);
            q.y = 0x3F80u | (bf16_rne(xv.y) << 16);
            q.z = 0x3F80u | (bf16_rne(xv.z) << 16);
            q.w = 0x3F80u | (bf16_rne(xv.w) << 16);
            reinterpret_cast<u32x4*>(Q)[id * 32 + f4] = q;
        }
        return;
    }
    __shared__ int hist[256];
    __shared__ int scan[256];
    __shared__ int cur[256];
    __shared__ int bscan[256];
    int b = blockIdx.x;
    if (t < 256) {
        bscan[t] = (t < NBKT) ? min(gcur[t], BCAP) : 0;
        hist[t] = 0;
    }
    __syncthreads();
    for (int d = 1; d < 256; d <<= 1) {
        int v = (t < 256 && t >= d) ? bscan[t - d] : 0;
        __syncthreads();
        if (t < 256) bscan[t] += v;
        __syncthreads();
    }
    int cnt = min(gcur[b], BCAP);
    int gstart = (b > 0) ? bscan[b - 1] : 0;
    const unsigned long long* eb = ebuf + (size_t)b * BCAP;
    unsigned long long rec[8];
#pragma unroll
    for (int k = 0; k < 8; ++k) {
        int idx = k * 1024 + t;
        rec[k] = 0;
        if (idx < cnt) {
            rec[k] = eb[idx];
            atomicAdd(&hist[(int)(rec[k] >> 32)], 1);
        }
    }
    __syncthreads();
    if (t < 256) scan[t] = hist[t];
    __syncthreads();
    for (int d = 1; d < 256; d <<= 1) {
        int v = (t < 256 && t >= d) ? scan[t - d] : 0;
        __syncthreads();
        if (t < 256) scan[t] += v;
        __syncthreads();
    }
    if (t < 256) {
        int excl = scan[t] - hist[t];
        cur[t] = excl;
        int row = b * 256 + t;
        if (row < NN) offsets[row] = gstart + excl;
    }
    if (b == NBKT - 1 && t == 0) offsets[NN] = gstart + cnt;
    __syncthreads();
#pragma unroll
    for (int k = 0; k < 8; ++k) {
        int idx = k * 1024 + t;
        if (idx < cnt) {
            int lr = (int)(rec[k] >> 32);
            int p = atomicAdd(&cur[lr], 1);
            gedges[gstart + p] = (unsigned)(rec[k] & 0xFFFFFFFFu);
        }
    }
}

// ---------- gather: one wave per 2 rows, CSR, uniform fast-path loads ------
__global__ __launch_bounds__(256)
void k_gather(const int* __restrict__ offsets, const unsigned* __restrict__ gedges,
              const unsigned* __restrict__ Q, unsigned* __restrict__ Hnb) {
    int t = blockIdx.x * blockDim.x + threadIdx.x;
    int wv = t >> 6;
    int lane = t & 63;
    int ra = wv * 2, rb = ra + 1;   // NN even
    if (ra >= NN) return;
    int ba = offsets[ra];
    int bb = offsets[rb];           // == end of ra
    int eb2 = offsets[rb + 1];
    int dega = bb - ba, degb = eb2 - bb;
    int nmax = (max(dega, degb) + 3) >> 2;
    const u32x2* Q2 = reinterpret_cast<const u32x2*>(Q);
    const unsigned padrec = PADCOL;  // col=50000 (zero row), adj=0
    float da0 = 0.f, da1 = 0.f, ha0 = 0.f, ha1 = 0.f;
    float db0 = 0.f, db1 = 0.f, hb0 = 0.f, hb1 = 0.f;
    for (int c = 0; c < nmax; ++c) {
        int ia = ba + c * 4, ib = bb + c * 4;
        unsigned ea[4], ebv[4];
        if (ia + 4 <= bb) {             // wave-uniform fast path
#pragma unroll
            for (int i = 0; i < 4; ++i) ea[i] = gedges[ia + i];
        } else {
#pragma unroll
            for (int i = 0; i < 4; ++i)
                ea[i] = (ia + i < bb) ? gedges[ia + i] : padrec;
        }
        if (ib + 4 <= eb2) {            // wave-uniform fast path
#pragma unroll
            for (int i = 0; i < 4; ++i) ebv[i] = gedges[ib + i];
        } else {
#pragma unroll
            for (int i = 0; i < 4; ++i)
                ebv[i] = (ib + i < eb2) ? gedges[ib + i] : padrec;
        }
#pragma unroll
        for (int i = 0; i < 4; ++i) {
            unsigned ca = ea[i] & 0xFFFFu, cb = ebv[i] & 0xFFFFu;
            float aa = __half2float(__ushort_as_half((unsigned short)(ea[i] >> 16)));
            float ab = __half2float(__ushort_as_half((unsigned short)(ebv[i] >> 16)));
            u32x2 qa = Q2[(int)ca * 64 + lane];
            u32x2 qb = Q2[(int)cb * 64 + lane];
            da0 += __uint_as_float(qa.x << 16);
            da1 += __uint_as_float(qa.y << 16);
            ha0 += aa * __uint_as_float(qa.x & 0xFFFF0000u);
            ha1 += aa * __uint_as_float(qa.y & 0xFFFF0000u);
            db0 += __uint_as_float(qb.x << 16);
            db1 += __uint_as_float(qb.y << 16);
            hb0 += ab * __uint_as_float(qb.x & 0xFFFF0000u);
            hb1 += ab * __uint_as_float(qb.y & 0xFFFF0000u);
        }
    }
    float oa0 = (da0 == 0.f) ? 0.f : ha0 / da0;
    float oa1 = (da1 == 0.f) ? 0.f : ha1 / da1;
    float ob0 = (db0 == 0.f) ? 0.f : hb0 / db0;
    float ob1 = (db1 == 0.f) ? 0.f : hb1 / db1;
    Hnb[ra * 64 + lane] = bf16_rne(oa0) | (bf16_rne(oa1) << 16);
    Hnb[rb * 64 + lane] = bf16_rne(ob0) | (bf16_rne(ob1) << 16);
}

// ---------- out = elu(Hn @ W) via MFMA bf16 ----------
__global__ __launch_bounds__(256)
void k_gemm(const unsigned* __restrict__ Hnb, const float* __restrict__ W,
            float* __restrict__ out) {
    __shared__ short Wb[128 * 128];  // 32KB: [((t*4+ks)*64 + l)*8 + j]
    int tid = threadIdx.x;

#pragma unroll
    for (int i = 0; i < 8; ++i) {
        int c = tid + i * 256;            // 0..2047
        int nl = c & 15;
        int t8 = (c >> 4) & 7;
        int ks = (c >> 7) & 3;
        int lh = (c >> 9) & 3;
        int l = nl | (lh << 4);
        int n = t8 * 16 + nl;
        int k0 = ks * 32 + lh * 8;
        short v[8];
#pragma unroll
        for (int j = 0; j < 8; ++j)
            v[j] = (short)bf16_rne(W[(k0 + j) * 128 + n]);
        *reinterpret_cast<bf16x8*>(&Wb[((t8 * 4 + ks) * 64 + l) * 8]) =
            *reinterpret_cast<bf16x8*>(v);
    }
    __syncthreads();

    int wave = tid >> 6, lane = tid & 63;
    int r0 = blockIdx.x * 64 + wave * 16;
    int mrow = lane & 15;
    int kg = lane >> 4;
    int arow = min(r0 + mrow, NN - 1);
    const u32x4* H4 = reinterpret_cast<const u32x4*>(Hnb);

    bf16x8 a[4];
#pragma unroll
    for (int ks = 0; ks < 4; ++ks) {
        u32x4 v = H4[(size_t)arow * 16 + ks * 4 + kg];
        a[ks] = *reinterpret_cast<bf16x8*>(&v);
    }

    f32x4 acc[8];
#pragma unroll
    for (int t8 = 0; t8 < 8; ++t8) acc[t8] = (f32x4){0.f, 0.f, 0.f, 0.f};

#pragma unroll
    for (int t8 = 0; t8 < 8; ++t8) {
#pragma unroll
        for (int ks = 0; ks < 4; ++ks) {
            bf16x8 b = *reinterpret_cast<const bf16x8*>(
                &Wb[((t8 * 4 + ks) * 64 + lane) * 8]);
            acc[t8] = __builtin_amdgcn_mfma_f32_16x16x32_bf16(a[ks], b, acc[t8], 0, 0, 0);
        }
    }

    // C/D layout: col = lane&15, row = (lane>>4)*4 + reg  [m89-verified]
    int colb = lane & 15;
    int rsub = (lane >> 4) * 4;
#pragma unroll
    for (int t8 = 0; t8 < 8; ++t8) {
#pragma unroll
        for (int rg = 0; rg < 4; ++rg) {
            int row = r0 + rsub + rg;
            if (row < NN) {
                float v = acc[t8][rg];
                float o = (v > 0.f) ? v : (__expf(v) - 1.0f);
                __builtin_nontemporal_store(o, &out[(size_t)row * 128 + t8 * 16 + colb]);
            }
        }
    }
}

// ================= fallback (atomic scatter) if ws is small =================
__global__ void k_init_fb(float* __restrict__ denomH, int* __restrict__ flags) {
    int i = blockIdx.x * blockDim.x + threadIdx.x;
    const int total4 = (2 * NF) / 4;
    if (i < total4)
        reinterpret_cast<float4*>(denomH)[i] = make_float4(0.f, 0.f, 0.f, 0.f);
    if (i < NN) flags[i] = 0;
}

__global__ void k_flags_fb(const int* __restrict__ ids, int* __restrict__ flags) {
    int i = blockIdx.x * blockDim.x + threadIdx.x;
    if (i < NT) flags[ids[i]] = 1;
}

__global__ __launch_bounds__(256)
void k_edge_fb(const int* __restrict__ rows, const int* __restrict__ cols,
               const float* __restrict__ adj, const float* __restrict__ M,
               const int* __restrict__ flags, const float* __restrict__ x,
               float* __restrict__ denom, float* __restrict__ H) {
    int t = blockIdx.x * blockDim.x + threadIdx.x;
    int e = t >> 6;
    int lane = t & 63;
    if (e >= NE) return;
    int r = rows[e], c = cols[e];
    float a = adj[e];
#pragma unroll
    for (int i = 0; i < 2; ++i) {
        int f = lane + i * 64;
        float m = M[c * FF + f];
        float me = flags[c] ? 1.0f : 1.0f / (1.0f + __expf(-m));
        float xv = x[c * FF + f];
        unsafeAtomicAdd(&denom[r * FF + f], me);
        unsafeAtomicAdd(&H[r * FF + f], a * me * xv);
    }
}

__global__ __launch_bounds__(256)
void k_norm_fb(const float* __restrict__ H, const float* __restrict__ denom,
               float* __restrict__ Hn) {
    int i = blockIdx.x * blockDim.x + threadIdx.x;
    if (i >= NF) return;
    float d = denom[i];
    Hn[i] = (d == 0.f) ? 0.f : H[i] / d;
}

__global__ __launch_bounds__(256)
void k_gemm_fb(const float* __restrict__ Hn, const float* __restrict__ W,
               float* __restrict__ out) {
    __shared__ float Ws[128][128];
    __shared__ float Hs[32][128];
    int tid = threadIdx.x;
    const float4* W4 = reinterpret_cast<const float4*>(W);
    float4* Ws4 = reinterpret_cast<float4*>(&Ws[0][0]);
#pragma unroll
    for (int i = 0; i < 16; ++i) Ws4[tid + i * 256] = W4[tid + i * 256];
    int r0 = blockIdx.x * 32;
    const float4* H4 = reinterpret_cast<const float4*>(Hn);
    float4* Hs4 = reinterpret_cast<float4*>(&Hs[0][0]);
#pragma unroll
    for (int i = 0; i < 4; ++i) {
        int m = tid + i * 256;
        int r = m >> 5, k4 = m & 31;
        int row = r0 + r;
        Hs4[m] = (row < NN) ? H4[row * 32 + k4] : make_float4(0.f, 0.f, 0.f, 0.f);
    }
    __syncthreads();
    int c = tid & 127, rg = tid >> 7;
    float acc[16];
#pragma unroll
    for (int i = 0; i < 16; ++i) acc[i] = 0.f;
    for (int k = 0; k < 128; k += 4) {
        float w0 = Ws[k][c], w1 = Ws[k + 1][c], w2 = Ws[k + 2][c], w3 = Ws[k + 3][c];
#pragma unroll
        for (int i = 0; i < 16; ++i) {
            float4 h = *reinterpret_cast<const float4*>(&Hs[rg * 16 + i][k]);
            acc[i] += h.x * w0 + h.y * w1 + h.z * w2 + h.w * w3;
        }
    }
#pragma unroll
    for (int i = 0; i < 16; ++i) {
        int row = r0 + rg * 16 + i;
        if (row < NN) {
            float v = acc[i];
            out[row * 128 + c] = (v > 0.f) ? v : (__expf(v) - 1.0f);
        }
    }
}

extern "C" void kernel_launch(void* const* d_in, const int* in_sizes, int n_in,
                              void* d_out, int out_size, void* d_ws, size_t ws_size,
                              hipStream_t stream) {
    const float* x     = (const float*)d_in[0];
    const int*   erows = (const int*)d_in[1];
    const int*   ecols = (const int*)d_in[2];
    const float* adj   = (const float*)d_in[3];
    const int*   train = (const int*)d_in[4];
    const float* M     = (const float*)d_in[5];
    const float* W     = (const float*)d_in[6];
    float* out = (float*)d_out;
    float* ws  = (float*)d_ws;

    // ws layout (4-byte units):
    // [Q: NF+FF][union: Hnb (NF/2) / ebuf (NBKT*BCAP*2)][gedges: NE]
    // [offsets: NN+1][gcur: 256]
    const size_t UNI = ((size_t)NBKT * BCAP * 2 > (size_t)NF / 2)
                           ? (size_t)NBKT * BCAP * 2 : (size_t)NF / 2;
    size_t fo = 0;
    unsigned* Q   = (unsigned*)(ws + fo); fo += NF + FF;
    unsigned* Hnb = (unsigned*)(ws + fo);
    unsigned long long* ebuf = (unsigned long long*)(ws + fo); fo += UNI;
    unsigned* gedges = (unsigned*)(ws + fo); fo += NE;
    int* offsets  = (int*)(ws + fo); fo += NN + 1;
    int* gcur     = (int*)(ws + fo); fo += 256;
    const size_t need = fo * 4;  // ~41.8 MB

    if (ws_size >= need) {
        k_init<<<1, 256, 0, stream>>>(gcur);
        k_sp<<<P1BLK + PACKB, 1024, 0, stream>>>(
            erows, ecols, adj, M, x, Q, gcur, ebuf);
        k_pass2<<<NBKT + TRNB, 1024, 0, stream>>>(
            gcur, ebuf, gedges, offsets, train, x, Q);
        k_gather<<<((NN / 2) * 64 + 255) / 256, 256, 0, stream>>>(offsets, gedges, Q, Hnb);
        k_gemm<<<(NN + 63) / 64, 256, 0, stream>>>(Hnb, W, out);
    } else {
        float* denom = ws;
        float* H     = ws + NF;
        int* flags_fb = (int*)(ws + 2 * (size_t)NF);
        k_init_fb<<<(2 * NF / 4 + 255) / 256, 256, 0, stream>>>(denom, flags_fb);
        k_flags_fb<<<(NT + 255) / 256, 256, 0, stream>>>(train, flags_fb);
        k_edge_fb<<<((size_t)NE * 64 + 255) / 256, 256, 0, stream>>>(
            erows, ecols, adj, M, flags_fb, x, denom, H);
        k_norm_fb<<<(NF + 255) / 256, 256, 0, stream>>>(H, denom, denom);
        k_gemm_fb<<<(NN + 31) / 32, 256, 0, stream>>>(denom, W, out);
    }
}

// Round 12
// 107.117 us; speedup vs baseline: 1.0196x; 1.0196x over previous
//
#include <hip/hip_runtime.h>
#include <hip/hip_fp16.h>

#define NN 50000      // nodes
#define FF 128        // features
#define NE 800000     // edges
#define NT 5000       // train ids
#define NF (NN * FF)  // 6,400,000
#define NBKT 196      // coarse buckets: row>>8 in [0,196)
#define BCAP 8192     // bucket capacity (avg 4082)
#define PADCOL 50000u // zero Q row
#define P1BLK 98      // pass1 edge-scatter blocks
#define TRNN (NT * 32)                   // train overwrite items
#define TRNB ((TRNN + 1023) / 1024)      // 157

typedef __attribute__((ext_vector_type(8))) short bf16x8;
typedef __attribute__((ext_vector_type(4))) float f32x4;
typedef __attribute__((ext_vector_type(4))) unsigned u32x4;
typedef __attribute__((ext_vector_type(2))) unsigned u32x2;
typedef __attribute__((ext_vector_type(4))) int i32x4;

__device__ __forceinline__ unsigned bf16_rne(float f) {
    unsigned u = __float_as_uint(f);
    return (u + 0x7FFFu + ((u >> 16) & 1u)) >> 16;
}

// ---------- pack Q[n][f] = (bf16(sigmoid) | bf16(sig*x)<<16); +gcur zero ----
__global__ void k_pack(const float* __restrict__ M, const float* __restrict__ x,
                       unsigned* __restrict__ Q, int* __restrict__ gcur) {
    int i4 = blockIdx.x * blockDim.x + threadIdx.x;
    if (i4 < 256) gcur[i4] = 0;
    if (i4 >= NF / 4 + FF / 4) return;
    u32x4* Q4 = reinterpret_cast<u32x4*>(Q);
    if (i4 >= NF / 4) {  // zero pad row (node NN)
        u32x4 z = {0, 0, 0, 0};
        Q4[i4] = z;
        return;
    }
    f32x4 m = __builtin_nontemporal_load(reinterpret_cast<const f32x4*>(M) + i4);
    f32x4 xv = __builtin_nontemporal_load(reinterpret_cast<const f32x4*>(x) + i4);
    float me0 = 1.0f / (1.0f + __expf(-m.x));
    float me1 = 1.0f / (1.0f + __expf(-m.y));
    float me2 = 1.0f / (1.0f + __expf(-m.z));
    float me3 = 1.0f / (1.0f + __expf(-m.w));
    u32x4 q;
    q.x = bf16_rne(me0) | (bf16_rne(me0 * xv.x) << 16);
    q.y = bf16_rne(me1) | (bf16_rne(me1 * xv.y) << 16);
    q.z = bf16_rne(me2) | (bf16_rne(me2 * xv.z) << 16);
    q.w = bf16_rne(me3) | (bf16_rne(me3 * xv.w) << 16);
    Q4[i4] = q;
}

// ---------- pass1 (blocks 0..97): coarse bucket scatter ----------
// blocks 98..: train-row overwrite (me=1, g=bf16(x)) -- runs after pack.
__global__ __launch_bounds__(1024)
void k_pass1(const int* __restrict__ rows, const int* __restrict__ cols,
             const float* __restrict__ adj, const int* __restrict__ train,
             const float* __restrict__ x, unsigned* __restrict__ Q,
             int* __restrict__ gcur, unsigned long long* __restrict__ ebuf) {
    int t = threadIdx.x;
    if (blockIdx.x >= P1BLK) {
        // ---- train overwrite part ----
        int g = (blockIdx.x - P1BLK) * 1024 + t;
        if (g < TRNN) {
            int ti = g >> 5;       // train index
            int f4 = g & 31;       // which float4 of the row
            int id = train[ti];
            f32x4 xv = reinterpret_cast<const f32x4*>(x)[id * 32 + f4];
            u32x4 q;
            q.x = 0x3F80u | (bf16_rne(xv.x) << 16);
            q.y = 0x3F80u | (bf16_rne(xv.y) << 16);
            q.z = 0x3F80u | (bf16_rne(xv.z) << 16);
            q.w = 0x3F80u | (bf16_rne(xv.w) << 16);
            reinterpret_cast<u32x4*>(Q)[id * 32 + f4] = q;
        }
        return;
    }
    __shared__ int hist[256];
    __shared__ int cur[256];
    if (t < 256) hist[t] = 0;
    __syncthreads();
    int base = blockIdx.x * 8192;
    int r[8], c[8], bkt[8];
    float a[8];
#pragma unroll
    for (int k = 0; k < 8; ++k) {
        int idx = base + k * 1024 + t;
        bool v = idx < NE;
        r[k] = v ? rows[idx] : 0;
        c[k] = v ? cols[idx] : 0;
        a[k] = v ? adj[idx] : 0.f;
        bkt[k] = v ? (r[k] >> 8) : -1;
        if (v) atomicAdd(&hist[bkt[k]], 1);
    }
    __syncthreads();
    if (t < 256) {
        int cnt = hist[t];
        int b = 0;
        if (cnt > 0) b = atomicAdd(&gcur[t], cnt);
        cur[t] = b;
    }
    __syncthreads();
#pragma unroll
    for (int k = 0; k < 8; ++k) {
        if (bkt[k] >= 0) {
            int p = atomicAdd(&cur[bkt[k]], 1);
            if (p < BCAP) {
                unsigned h = (unsigned)__half_as_ushort(__float2half_rn(a[k]));
                unsigned pk = (unsigned)c[k] | (h << 16);
                ebuf[(size_t)bkt[k] * BCAP + p] =
                    ((unsigned long long)(r[k] & 255) << 32) | pk;
            }
        }
    }
}

// ---------- pass2: per-bucket fine CSR; inline bucket-base scan ----------
__global__ __launch_bounds__(1024)
void k_pass2(const int* __restrict__ gcur,
             const unsigned long long* __restrict__ ebuf,
             unsigned* __restrict__ gedges, int* __restrict__ offsets) {
    __shared__ int hist[256];
    __shared__ int scan[256];
    __shared__ int cur[256];
    __shared__ int bscan[256];
    int b = blockIdx.x;
    int t = threadIdx.x;
    if (t < 256) {
        bscan[t] = (t < NBKT) ? min(gcur[t], BCAP) : 0;
        hist[t] = 0;
    }
    __syncthreads();
    for (int d = 1; d < 256; d <<= 1) {
        int v = (t < 256 && t >= d) ? bscan[t - d] : 0;
        __syncthreads();
        if (t < 256) bscan[t] += v;
        __syncthreads();
    }
    int cnt = min(gcur[b], BCAP);
    int gstart = (b > 0) ? bscan[b - 1] : 0;
    const unsigned long long* eb = ebuf + (size_t)b * BCAP;
    unsigned long long rec[8];
#pragma unroll
    for (int k = 0; k < 8; ++k) {
        int idx = k * 1024 + t;
        rec[k] = 0;
        if (idx < cnt) {
            rec[k] = eb[idx];
            atomicAdd(&hist[(int)(rec[k] >> 32)], 1);
        }
    }
    __syncthreads();
    if (t < 256) scan[t] = hist[t];
    __syncthreads();
    for (int d = 1; d < 256; d <<= 1) {
        int v = (t < 256 && t >= d) ? scan[t - d] : 0;
        __syncthreads();
        if (t < 256) scan[t] += v;
        __syncthreads();
    }
    if (t < 256) {
        int excl = scan[t] - hist[t];
        cur[t] = excl;
        int row = b * 256 + t;
        if (row < NN) offsets[row] = gstart + excl;
    }
    if (b == NBKT - 1 && t == 0) offsets[NN] = gstart + cnt;
    __syncthreads();
#pragma unroll
    for (int k = 0; k < 8; ++k) {
        int idx = k * 1024 + t;
        if (idx < cnt) {
            int lr = (int)(rec[k] >> 32);
            int p = atomicAdd(&cur[lr], 1);
            gedges[gstart + p] = (unsigned)(rec[k] & 0xFFFFFFFFu);
        }
    }
}

// ---------- gather: one wave per 2 rows, CSR, uniform fast-path loads ------
__global__ __launch_bounds__(256)
void k_gather(const int* __restrict__ offsets, const unsigned* __restrict__ gedges,
              const unsigned* __restrict__ Q, unsigned* __restrict__ Hnb) {
    int t = blockIdx.x * blockDim.x + threadIdx.x;
    int wv = t >> 6;
    int lane = t & 63;
    int ra = wv * 2, rb = ra + 1;   // NN even
    if (ra >= NN) return;
    int ba = offsets[ra];
    int bb = offsets[rb];           // == end of ra
    int eb2 = offsets[rb + 1];
    int dega = bb - ba, degb = eb2 - bb;
    int nmax = (max(dega, degb) + 3) >> 2;
    const u32x2* Q2 = reinterpret_cast<const u32x2*>(Q);
    const unsigned padrec = PADCOL;  // col=50000 (zero row), adj=0
    float da0 = 0.f, da1 = 0.f, ha0 = 0.f, ha1 = 0.f;
    float db0 = 0.f, db1 = 0.f, hb0 = 0.f, hb1 = 0.f;
    for (int c = 0; c < nmax; ++c) {
        int ia = ba + c * 4, ib = bb + c * 4;
        unsigned ea[4], ebv[4];
        if (ia + 4 <= bb) {             // wave-uniform fast path
#pragma unroll
            for (int i = 0; i < 4; ++i) ea[i] = gedges[ia + i];
        } else {
#pragma unroll
            for (int i = 0; i < 4; ++i)
                ea[i] = (ia + i < bb) ? gedges[ia + i] : padrec;
        }
        if (ib + 4 <= eb2) {            // wave-uniform fast path
#pragma unroll
            for (int i = 0; i < 4; ++i) ebv[i] = gedges[ib + i];
        } else {
#pragma unroll
            for (int i = 0; i < 4; ++i)
                ebv[i] = (ib + i < eb2) ? gedges[ib + i] : padrec;
        }
#pragma unroll
        for (int i = 0; i < 4; ++i) {
            unsigned ca = ea[i] & 0xFFFFu, cb = ebv[i] & 0xFFFFu;
            float aa = __half2float(__ushort_as_half((unsigned short)(ea[i] >> 16)));
            float ab = __half2float(__ushort_as_half((unsigned short)(ebv[i] >> 16)));
            u32x2 qa = Q2[(int)ca * 64 + lane];
            u32x2 qb = Q2[(int)cb * 64 + lane];
            da0 += __uint_as_float(qa.x << 16);
            da1 += __uint_as_float(qa.y << 16);
            ha0 += aa * __uint_as_float(qa.x & 0xFFFF0000u);
            ha1 += aa * __uint_as_float(qa.y & 0xFFFF0000u);
            db0 += __uint_as_float(qb.x << 16);
            db1 += __uint_as_float(qb.y << 16);
            hb0 += ab * __uint_as_float(qb.x & 0xFFFF0000u);
            hb1 += ab * __uint_as_float(qb.y & 0xFFFF0000u);
        }
    }
    float oa0 = (da0 == 0.f) ? 0.f : ha0 / da0;
    float oa1 = (da1 == 0.f) ? 0.f : ha1 / da1;
    float ob0 = (db0 == 0.f) ? 0.f : hb0 / db0;
    float ob1 = (db1 == 0.f) ? 0.f : hb1 / db1;
    Hnb[ra * 64 + lane] = bf16_rne(oa0) | (bf16_rne(oa1) << 16);
    Hnb[rb * 64 + lane] = bf16_rne(ob0) | (bf16_rne(ob1) << 16);
}

// ---------- out = elu(Hn @ W) via MFMA bf16 ----------
__global__ __launch_bounds__(256)
void k_gemm(const unsigned* __restrict__ Hnb, const float* __restrict__ W,
            float* __restrict__ out) {
    __shared__ short Wb[128 * 128];  // 32KB: [((t*4+ks)*64 + l)*8 + j]
    int tid = threadIdx.x;

#pragma unroll
    for (int i = 0; i < 8; ++i) {
        int c = tid + i * 256;            // 0..2047
        int nl = c & 15;
        int t8 = (c >> 4) & 7;
        int ks = (c >> 7) & 3;
        int lh = (c >> 9) & 3;
        int l = nl | (lh << 4);
        int n = t8 * 16 + nl;
        int k0 = ks * 32 + lh * 8;
        short v[8];
#pragma unroll
        for (int j = 0; j < 8; ++j)
            v[j] = (short)bf16_rne(W[(k0 + j) * 128 + n]);
        *reinterpret_cast<bf16x8*>(&Wb[((t8 * 4 + ks) * 64 + l) * 8]) =
            *reinterpret_cast<bf16x8*>(v);
    }
    __syncthreads();

    int wave = tid >> 6, lane = tid & 63;
    int r0 = blockIdx.x * 64 + wave * 16;
    int mrow = lane & 15;
    int kg = lane >> 4;
    int arow = min(r0 + mrow, NN - 1);
    const u32x4* H4 = reinterpret_cast<const u32x4*>(Hnb);

    bf16x8 a[4];
#pragma unroll
    for (int ks = 0; ks < 4; ++ks) {
        u32x4 v = H4[(size_t)arow * 16 + ks * 4 + kg];
        a[ks] = *reinterpret_cast<bf16x8*>(&v);
    }

    f32x4 acc[8];
#pragma unroll
    for (int t8 = 0; t8 < 8; ++t8) acc[t8] = (f32x4){0.f, 0.f, 0.f, 0.f};

#pragma unroll
    for (int t8 = 0; t8 < 8; ++t8) {
#pragma unroll
        for (int ks = 0; ks < 4; ++ks) {
            bf16x8 b = *reinterpret_cast<const bf16x8*>(
                &Wb[((t8 * 4 + ks) * 64 + lane) * 8]);
            acc[t8] = __builtin_amdgcn_mfma_f32_16x16x32_bf16(a[ks], b, acc[t8], 0, 0, 0);
        }
    }

    // C/D layout: col = lane&15, row = (lane>>4)*4 + reg  [m89-verified]
    int colb = lane & 15;
    int rsub = (lane >> 4) * 4;
#pragma unroll
    for (int t8 = 0; t8 < 8; ++t8) {
#pragma unroll
        for (int rg = 0; rg < 4; ++rg) {
            int row = r0 + rsub + rg;
            if (row < NN) {
                float v = acc[t8][rg];
                float o = (v > 0.f) ? v : (__expf(v) - 1.0f);
                __builtin_nontemporal_store(o, &out[(size_t)row * 128 + t8 * 16 + colb]);
            }
        }
    }
}

// ================= fallback (atomic scatter) if ws is small =================
__global__ void k_init_fb(float* __restrict__ denomH, int* __restrict__ flags) {
    int i = blockIdx.x * blockDim.x + threadIdx.x;
    const int total4 = (2 * NF) / 4;
    if (i < total4)
        reinterpret_cast<float4*>(denomH)[i] = make_float4(0.f, 0.f, 0.f, 0.f);
    if (i < NN) flags[i] = 0;
}

__global__ void k_flags_fb(const int* __restrict__ ids, int* __restrict__ flags) {
    int i = blockIdx.x * blockDim.x + threadIdx.x;
    if (i < NT) flags[ids[i]] = 1;
}

__global__ __launch_bounds__(256)
void k_edge_fb(const int* __restrict__ rows, const int* __restrict__ cols,
               const float* __restrict__ adj, const float* __restrict__ M,
               const int* __restrict__ flags, const float* __restrict__ x,
               float* __restrict__ denom, float* __restrict__ H) {
    int t = blockIdx.x * blockDim.x + threadIdx.x;
    int e = t >> 6;
    int lane = t & 63;
    if (e >= NE) return;
    int r = rows[e], c = cols[e];
    float a = adj[e];
#pragma unroll
    for (int i = 0; i < 2; ++i) {
        int f = lane + i * 64;
        float m = M[c * FF + f];
        float me = flags[c] ? 1.0f : 1.0f / (1.0f + __expf(-m));
        float xv = x[c * FF + f];
        unsafeAtomicAdd(&denom[r * FF + f], me);
        unsafeAtomicAdd(&H[r * FF + f], a * me * xv);
    }
}

__global__ __launch_bounds__(256)
void k_norm_fb(const float* __restrict__ H, const float* __restrict__ denom,
               float* __restrict__ Hn) {
    int i = blockIdx.x * blockDim.x + threadIdx.x;
    if (i >= NF) return;
    float d = denom[i];
    Hn[i] = (d == 0.f) ? 0.f : H[i] / d;
}

__global__ __launch_bounds__(256)
void k_gemm_fb(const float* __restrict__ Hn, const float* __restrict__ W,
               float* __restrict__ out) {
    __shared__ float Ws[128][128];
    __shared__ float Hs[32][128];
    int tid = threadIdx.x;
    const float4* W4 = reinterpret_cast<const float4*>(W);
    float4* Ws4 = reinterpret_cast<float4*>(&Ws[0][0]);
#pragma unroll
    for (int i = 0; i < 16; ++i) Ws4[tid + i * 256] = W4[tid + i * 256];
    int r0 = blockIdx.x * 32;
    const float4* H4 = reinterpret_cast<const float4*>(Hn);
    float4* Hs4 = reinterpret_cast<float4*>(&Hs[0][0]);
#pragma unroll
    for (int i = 0; i < 4; ++i) {
        int m = tid + i * 256;
        int r = m >> 5, k4 = m & 31;
        int row = r0 + r;
        Hs4[m] = (row < NN) ? H4[row * 32 + k4] : make_float4(0.f, 0.f, 0.f, 0.f);
    }
    __syncthreads();
    int c = tid & 127, rg = tid >> 7;
    float acc[16];
#pragma unroll
    for (int i = 0; i < 16; ++i) acc[i] = 0.f;
    for (int k = 0; k < 128; k += 4) {
        float w0 = Ws[k][c], w1 = Ws[k + 1][c], w2 = Ws[k + 2][c], w3 = Ws[k + 3][c];
#pragma unroll
        for (int i = 0; i < 16; ++i) {
            float4 h = *reinterpret_cast<const float4*>(&Hs[rg * 16 + i][k]);
            acc[i] += h.x * w0 + h.y * w1 + h.z * w2 + h.w * w3;
        }
    }
#pragma unroll
    for (int i = 0; i < 16; ++i) {
        int row = r0 + rg * 16 + i;
        if (row < NN) {
            float v = acc[i];
            out[row * 128 + c] = (v > 0.f) ? v : (__expf(v) - 1.0f);
        }
    }
}

extern "C" void kernel_launch(void* const* d_in, const int* in_sizes, int n_in,
                              void* d_out, int out_size, void* d_ws, size_t ws_size,
                              hipStream_t stream) {
    const float* x     = (const float*)d_in[0];
    const int*   erows = (const int*)d_in[1];
    const int*   ecols = (const int*)d_in[2];
    const float* adj   = (const float*)d_in[3];
    const int*   train = (const int*)d_in[4];
    const float* M     = (const float*)d_in[5];
    const float* W     = (const float*)d_in[6];
    float* out = (float*)d_out;
    float* ws  = (float*)d_ws;

    // ws layout (4-byte units):
    // [Q: NF+FF][union: Hnb (NF/2) / ebuf (NBKT*BCAP*2)][gedges: NE]
    // [offsets: NN+1][gcur: 256]
    const size_t UNI = ((size_t)NBKT * BCAP * 2 > (size_t)NF / 2)
                           ? (size_t)NBKT * BCAP * 2 : (size_t)NF / 2;
    size_t fo = 0;
    unsigned* Q   = (unsigned*)(ws + fo); fo += NF + FF;
    unsigned* Hnb = (unsigned*)(ws + fo);
    unsigned long long* ebuf = (unsigned long long*)(ws + fo); fo += UNI;
    unsigned* gedges = (unsigned*)(ws + fo); fo += NE;
    int* offsets  = (int*)(ws + fo); fo += NN + 1;
    int* gcur     = (int*)(ws + fo); fo += 256;
    const size_t need = fo * 4;  // ~41.8 MB

    if (ws_size >= need) {
        k_pack<<<(NF / 4 + FF / 4 + 255) / 256, 256, 0, stream>>>(M, x, Q, gcur);
        k_pass1<<<P1BLK + TRNB, 1024, 0, stream>>>(
            erows, ecols, adj, train, x, Q, gcur, ebuf);
        k_pass2<<<NBKT, 1024, 0, stream>>>(gcur, ebuf, gedges, offsets);
        k_gather<<<((NN / 2) * 64 + 255) / 256, 256, 0, stream>>>(offsets, gedges, Q, Hnb);
        k_gemm<<<(NN + 63) / 64, 256, 0, stream>>>(Hnb, W, out);
    } else {
        float* denom = ws;
        float* H     = ws + NF;
        int* flags_fb = (int*)(ws + 2 * (size_t)NF);
        k_init_fb<<<(2 * NF / 4 + 255) / 256, 256, 0, stream>>>(denom, flags_fb);
        k_flags_fb<<<(NT + 255) / 256, 256, 0, stream>>>(train, flags_fb);
        k_edge_fb<<<((size_t)NE * 64 + 255) / 256, 256, 0, stream>>>(
            erows, ecols, adj, M, flags_fb, x, denom, H);
        k_norm_fb<<<(NF + 255) / 256, 256, 0, stream>>>(H, denom, denom);
        k_gemm_fb<<<(NN + 31) / 32, 256, 0, stream>>>(denom, W, out);
    }
}